// Round 6
// baseline (247.321 us; speedup 1.0000x reference)
//
#include <hip/hip_runtime.h>
#include <hip/hip_bf16.h>

// S=1024, B=8, D=768, H=12, DH=64, PROMPT_NUM=8 (tokens=1016). I/O fp32.
// bf16 MFMA compute, fp32 accum. Attention: S^T = K*Q^T so the QK accumulator
// (row=key, col=q) IS the B-fragment of the 16x16x16 PV MFMA (P stays in
// registers). K/V tiles staged cooperatively in LDS, reg-buffered prefetch.
// R6: GEMM staging = m97 recipe (global_load_lds width=16, linear LDS).
// R7: attn P-pack via v_cvt_pk_bf16_f32; attn grid XCD-swizzle.
// R8: GEMM 2-phase LDS double-buffer (null in isolation; kept).
// R9: GEMM XCD swizzle (null; removed from qkv in R10).
// R10: qkv_gemm tile 128x128 -> 256x128, 8 waves/512 thr. Rationale: 4 nulls
//     show a structure-fixed ~2400 cyc/K-iter floor (matches learn_hip m97's
//     measured floor); only work-per-iter scales. 2x MFMA/iter/WG, half the
//     WGs, staged traffic 432->324 MB; n-fastest grid shares the A-panel
//     across 18 consecutive WGs and keeps W (3.4 MB) L2-resident per XCD.
// NOTE: MFMA16/GLD16 gated on __HIP_DEVICE_COMPILE__ — the host pass's
// __has_builtin() returns false for amdgcn builtins (R4 compile failure).

typedef unsigned short u16;
typedef __attribute__((ext_vector_type(8))) short short8;    // 8 bf16 (K=32 frag)
typedef __attribute__((ext_vector_type(4))) short short4v;   // 4 bf16 (K=16 frag)
typedef __attribute__((ext_vector_type(4))) float floatx4;   // MFMA C/D frag
typedef __attribute__((ext_vector_type(4))) unsigned short ushort4v;
typedef __attribute__((ext_vector_type(2))) unsigned int uint2v;

#define NB 8
#define NS 1024
#define NH 12
#define ND 768
#define DHD 64
#define TOKENS 1016
#define QKV_OUT_STRIDE 6291456  // S*B*D elements per output tensor

#if __has_builtin(__builtin_amdgcn_exp2f)
#define EXP2(x) __builtin_amdgcn_exp2f(x)
#else
#define EXP2(x) exp2f(x)
#endif

#if defined(__HIP_DEVICE_COMPILE__)
  #if __has_builtin(__builtin_amdgcn_mfma_f32_16x16x16bf16_1k)
    #define MFMA16(a, b, c) __builtin_amdgcn_mfma_f32_16x16x16bf16_1k(a, b, c, 0, 0, 0)
  #else
    #define MFMA16(a, b, c) __builtin_amdgcn_mfma_f32_16x16x16_bf16(a, b, c, 0, 0, 0)
  #endif
  // async global->LDS, 16B per lane; LDS dest = wave-uniform base + lane*16.
  #define GLD16(g, l)                                                        \
    __builtin_amdgcn_global_load_lds(                                        \
        (const __attribute__((address_space(1))) void*)(g),                  \
        (__attribute__((address_space(3))) void*)(l), 16, 0, 0)
#else
  #define MFMA16(a, b, c) (c)   // host pass: dead code, never executed
  #define GLD16(g, l) ((void)0)
#endif

__device__ __forceinline__ u16 f2bf(float f) {
  union { float f; unsigned u; } c; c.f = f;
  return (u16)((c.u + 0x7fffu + ((c.u >> 16) & 1u)) >> 16);  // RNE
}

// ---------------------------------------------------------------------------
// Kernel 0: fp32 -> bf16 for X, in_proj_weight, out_w. 4 elems/thread.
// ---------------------------------------------------------------------------
#define CVT_B0 6144   // X:  6291456/1024
#define CVT_B1 1728   // W:  1769472/1024
#define CVT_B2 576    // Ow: 589824/1024
__global__ __launch_bounds__(256) void cvt3(
    const float* __restrict__ s0, u16* __restrict__ d0,
    const float* __restrict__ s1, u16* __restrict__ d1,
    const float* __restrict__ s2, u16* __restrict__ d2) {
  int blk = blockIdx.x;
  const float* s; u16* d;
  if (blk < CVT_B0) { s = s0; d = d0; }
  else if (blk < CVT_B0 + CVT_B1) { s = s1; d = d1; blk -= CVT_B0; }
  else { s = s2; d = d2; blk -= CVT_B0 + CVT_B1; }
  const int i = (blk * 256 + (int)threadIdx.x) * 4;
  const float4 v = *(const float4*)(s + i);
  ushort4v o;
  o.x = f2bf(v.x); o.y = f2bf(v.y); o.z = f2bf(v.z); o.w = f2bf(v.w);
  *(ushort4v*)(d + i) = o;
}

// ---------------------------------------------------------------------------
// Kernel 1: QKV projection. 256x128 tile/WG, 8 waves (512 thr), wave tile
// 64x64 = 4x4 of 16x16x32 MFMA. 2-phase LDS double-buffer, GLD16 staging:
// A = 16 chunks (wave w: 2w, 2w+1), B = 8 chunks (wave w: w); chunk c covers
// rows c*16..c*16+15, lane l -> row c*16+(l>>2), col (l&3)*8.
// Grid (n=18 fastest, m=32): consecutive WGs share the 393 KB A-panel; W is
// 3.4 MB total -> L2-resident per XCD after first m-block.
// ---------------------------------------------------------------------------
#define QKV_STAGE(bufA, bufB, k0)                                            \
  do {                                                                       \
    GLD16(ga0 + (k0), &bufA[cA0 * 16][0]);                                   \
    GLD16(ga1 + (k0), &bufA[cA0 * 16 + 16][0]);                              \
    GLD16(gb0 + (k0), &bufB[cB * 16][0]);                                    \
  } while (0)

#define QKV_COMPUTE(bufA, bufB)                                              \
  do {                                                                       \
    short8 af[4], bfr[4];                                                    \
    _Pragma("unroll")                                                        \
    for (int mt = 0; mt < 4; ++mt)                                           \
      af[mt] = *(const short8*)&bufA[wm * 64 + mt * 16 + l15][quad * 8];     \
    _Pragma("unroll")                                                        \
    for (int nt = 0; nt < 4; ++nt)                                           \
      bfr[nt] = *(const short8*)&bufB[wn * 64 + nt * 16 + l15][quad * 8];    \
    _Pragma("unroll")                                                        \
    for (int mt = 0; mt < 4; ++mt)                                           \
      _Pragma("unroll")                                                      \
      for (int nt = 0; nt < 4; ++nt)                                         \
        acc[mt][nt] = __builtin_amdgcn_mfma_f32_16x16x32_bf16(               \
            af[mt], bfr[nt], acc[mt][nt], 0, 0, 0);                          \
  } while (0)

__global__ __launch_bounds__(512) void qkv_gemm(
    const u16* __restrict__ Xb, const u16* __restrict__ Wb,
    const float* __restrict__ bias, float* __restrict__ out) {
  __shared__ __align__(16) u16 p0A[256][32];
  __shared__ __align__(16) u16 p0B[128][32];
  __shared__ __align__(16) u16 p1A[256][32];
  __shared__ __align__(16) u16 p1B[128][32];
  const int tid = threadIdx.x;
  const int lane = tid & 63, wave = tid >> 6;
  const int l15 = lane & 15, quad = lane >> 4;
  const int wm = wave & 3;        // m 64-chunk (0..3)
  const int wn = wave >> 2;       // n 64-chunk (0..1)
  const int mblk = blockIdx.y * 256;
  const int nblk = blockIdx.x * 128;

  floatx4 acc[4][4];
#pragma unroll
  for (int i2 = 0; i2 < 4; ++i2)
#pragma unroll
    for (int j = 0; j < 4; ++j) acc[i2][j] = (floatx4)0.f;

  // staging geometry: wave w loads A chunks 2w, 2w+1 and B chunk w
  const int lr = lane >> 2;
  const int lc = (lane & 3) * 8;
  const int cA0 = wave * 2;
  const int cB = wave;
  const int rA0 = cA0 * 16 + lr, rA1 = rA0 + 16;
  const int gm0 = mblk + rA0, gm1 = mblk + rA1;
  // X is (S,B,D): row gm -> b=gm>>10, s=gm&1023
  const u16* ga0 = Xb + ((gm0 & 1023) * NB + (gm0 >> 10)) * ND + lc;
  const u16* ga1 = Xb + ((gm1 & 1023) * NB + (gm1 >> 10)) * ND + lc;
  const u16* gb0 = Wb + (nblk + cB * 16 + lr) * ND + lc;

  QKV_STAGE(p0A, p0B, 0);
  __syncthreads();
  for (int kt = 0; kt < 24; kt += 2) {
    // phase A: prefetch tile kt+1 into p1, compute p0 (kt+1 <= 23 always)
    QKV_STAGE(p1A, p1B, (kt + 1) * 32);
    QKV_COMPUTE(p0A, p0B);
    __syncthreads();   // drains vmcnt(0): p1 ready; p0 reads fenced
    // phase B: prefetch tile kt+2 into p0, compute p1
    if (kt + 2 < 24) QKV_STAGE(p0A, p0B, (kt + 2) * 32);
    QKV_COMPUTE(p1A, p1B);
    __syncthreads();
  }

#pragma unroll
  for (int mt = 0; mt < 4; ++mt) {
#pragma unroll
    for (int r = 0; r < 4; ++r) {
      const int gm = mblk + wm * 64 + mt * 16 + quad * 4 + r;
      const int b = gm >> 10, s = gm & 1023;
#pragma unroll
      for (int nt = 0; nt < 4; ++nt) {
        const int gn = nblk + wn * 64 + nt * 16 + l15;
        const int seg = gn / ND;
        const int nn = gn - seg * ND;
        out[seg * QKV_OUT_STRIDE + (s * NB + b) * ND + nn] = acc[mt][nt][r] + bias[gn];
      }
    }
  }
}

// ---------------------------------------------------------------------------
// Kernel 1b: prep. z=0: K fp32 -> Kb[b,h,s,c] bf16. z=1: V -> Vt[b,h,c,s].
// ---------------------------------------------------------------------------
__global__ __launch_bounds__(256) void prep(
    const float* __restrict__ K, const float* __restrict__ V,
    u16* __restrict__ Kb, u16* __restrict__ Vt) {
  __shared__ u16 tile[DHD][40];
  const int t = threadIdx.x;
  const int bh = blockIdx.y;
  const int b = bh / NH, h = bh % NH;
  const int s0 = blockIdx.x * 32;
  const int sl = t >> 3;
  const int c0 = (t & 7) * 8;
  const int s = s0 + sl;
  if (blockIdx.z == 0) {
    const float* src = K + ((s * NB + b) * NH + h) * DHD + c0;
    const float4 v0 = *(const float4*)src;
    const float4 v1 = *(const float4*)(src + 4);
    short8 o;
    o[0] = f2bf(v0.x); o[1] = f2bf(v0.y); o[2] = f2bf(v0.z); o[3] = f2bf(v0.w);
    o[4] = f2bf(v1.x); o[5] = f2bf(v1.y); o[6] = f2bf(v1.z); o[7] = f2bf(v1.w);
    *(short8*)(Kb + ((size_t)bh * NS + s) * DHD + c0) = o;
  } else {
    const float* src = V + ((s * NB + b) * NH + h) * DHD + c0;
    const float4 v0 = *(const float4*)src;
    const float4 v1 = *(const float4*)(src + 4);
    tile[c0 + 0][sl] = f2bf(v0.x); tile[c0 + 1][sl] = f2bf(v0.y);
    tile[c0 + 2][sl] = f2bf(v0.z); tile[c0 + 3][sl] = f2bf(v0.w);
    tile[c0 + 4][sl] = f2bf(v1.x); tile[c0 + 5][sl] = f2bf(v1.y);
    tile[c0 + 6][sl] = f2bf(v1.z); tile[c0 + 7][sl] = f2bf(v1.w);
    __syncthreads();
    const int c = t >> 2;
    const int so = (t & 3) * 8;
    *(short8*)(Vt + ((size_t)bh * DHD + c) * NS + s0 + so) =
        *(const short8*)&tile[c][so];
  }
}

// ---------------------------------------------------------------------------
// Kernel 2: flash attention. WG = 128 q of one (b,h); wave = 32 q (2 Q frags).
// 16 outer iters of 64-key tiles staged in LDS (reg-buffered prefetch).
// Register-only P path:
//   S^T = mfma32(K-frag, Q-frag)  (C row=key, col=q)
//   p = exp2(fma(s,C1,C0)); pack via v_cvt_pk_bf16_f32 -> B-frag of 16x16x16
//   O^T[g] = mfma16(V-frag, p, O^T[g])
// Grid is XCD-swizzled: HW linear id L -> XCD L&7; all 8 q-blocks of one
// (b,h) get the same L&7 so the 256 KB K/V is L2-resident per XCD.
// ---------------------------------------------------------------------------
__global__ __launch_bounds__(256) void attn(
    const float* __restrict__ Q, const u16* __restrict__ Kb,
    const u16* __restrict__ Vt, u16* __restrict__ mix) {
  __shared__ __align__(16) u16 Kt[64][72];  // [key_local][c]
  __shared__ __align__(16) u16 Vs[64][72];  // [c][key_local]
  const int tid = threadIdx.x;
  const int lane = tid & 63, wave = tid >> 6;
  const int l15 = lane & 15, quad = lane >> 4;
  // XCD swizzle: L in [0,768). xcd = L&7, t = L>>3 in [0,96).
  // bh = xcd + 8*(t>>3)  (12 bh per XCD), qx = t&7. Bijective.
  const int L = (int)blockIdx.x + 8 * (int)blockIdx.y;
  const int xcd = L & 7, tt = L >> 3;
  const int bh = xcd + 8 * (tt >> 3);
  const int qx = tt & 7;
  const int b = bh / NH, h = bh % NH;
  const int qb = qx * 128 + wave * 32;

  // Q B-frags: n=l15 -> q, k=quad*8+j -> channel. fp32 -> bf16 once.
  short8 qf[2][2];
  bool qmask[2];
#pragma unroll
  for (int j = 0; j < 2; ++j) {
    const int qj = qb + j * 16 + l15;
    qmask[j] = (qj == 0 || qj >= TOKENS);
    const float* qp = Q + ((qj * NB + b) * NH + h) * DHD + quad * 8;
#pragma unroll
    for (int e = 0; e < 8; ++e) {
      qf[j][0][e] = (short)f2bf(qp[e]);
      qf[j][1][e] = (short)f2bf(qp[32 + e]);
    }
  }

  floatx4 O[2][4];
#pragma unroll
  for (int j = 0; j < 2; ++j)
#pragma unroll
    for (int g = 0; g < 4; ++g) O[j][g] = (floatx4)0.f;
  float li[2] = {0.f, 0.f};

  const u16* kg = Kb + (size_t)bh * NS * DHD;  // rows of 64 shorts (s,c)
  const u16* vg = Vt + (size_t)bh * DHD * NS;  // rows of 1024 shorts (c,s)

  const float C1 = 0.125f * 1.44269504089f;    // 1/sqrt(64) * log2(e)
  const float C0 = -10.0f * 1.44269504089f;

  // staging: thread t covers row t>>2 (0..63), 32B chunk (t&3)*16 shorts
  const int srow = tid >> 2;
  const int scol = (tid & 3) * 16;

  short8 pk0, pk1, pv0, pv1;
  {
    pk0 = *(const short8*)(kg + srow * DHD + scol);
    pk1 = *(const short8*)(kg + srow * DHD + scol + 8);
    pv0 = *(const short8*)(vg + srow * NS + scol);
    pv1 = *(const short8*)(vg + srow * NS + scol + 8);
  }

  for (int it = 0; it < 16; ++it) {
    *(short8*)&Kt[srow][scol] = pk0;
    *(short8*)&Kt[srow][scol + 8] = pk1;
    *(short8*)&Vs[srow][scol] = pv0;
    *(short8*)&Vs[srow][scol + 8] = pv1;
    __syncthreads();
    if (it < 15) {
      const int k0 = (it + 1) * 64;
      pk0 = *(const short8*)(kg + (k0 + srow) * DHD + scol);
      pk1 = *(const short8*)(kg + (k0 + srow) * DHD + scol + 8);
      pv0 = *(const short8*)(vg + srow * NS + k0 + scol);
      pv1 = *(const short8*)(vg + srow * NS + k0 + scol + 8);
    }
    const bool mrow = (it == 15) && (quad >= 2);  // keys >= 1016 rows
#pragma unroll
    for (int sub = 0; sub < 4; ++sub) {
      const short8 kf0 = *(const short8*)&Kt[sub * 16 + l15][quad * 8];
      const short8 kf1 = *(const short8*)&Kt[sub * 16 + l15][32 + quad * 8];
      short4v pb[2];
#pragma unroll
      for (int j = 0; j < 2; ++j) {
        floatx4 a = (floatx4)0.f;
        a = __builtin_amdgcn_mfma_f32_16x16x32_bf16(kf0, qf[j][0], a, 0, 0, 0);
        a = __builtin_amdgcn_mfma_f32_16x16x32_bf16(kf1, qf[j][1], a, 0, 0, 0);
        float p[4];
#pragma unroll
        for (int r = 0; r < 4; ++r) p[r] = EXP2(fmaf(a[r], C1, C0));
        if (sub == 3 && mrow && qmask[j]) {
#pragma unroll
          for (int r = 0; r < 4; ++r) p[r] = 0.f;
        }
        li[j] += (p[0] + p[1]) + (p[2] + p[3]);
        // pack 4 fp32 -> 4 bf16 via v_cvt_pk_bf16_f32 (RNE, same as f2bf)
        __hip_bfloat162 w0 = __float22bfloat162_rn(make_float2(p[0], p[1]));
        __hip_bfloat162 w1 = __float22bfloat162_rn(make_float2(p[2], p[3]));
        uint2v pw;
        pw.x = *(const unsigned*)&w0;
        pw.y = *(const unsigned*)&w1;
        pb[j] = __builtin_bit_cast(short4v, pw);
      }
#pragma unroll
      for (int g = 0; g < 4; ++g) {
        const short4v vf = *(const short4v*)&Vs[g * 16 + l15][sub * 16 + quad * 4];
        O[0][g] = MFMA16(vf, pb[0], O[0][g]);
        O[1][g] = MFMA16(vf, pb[1], O[1][g]);
      }
    }
    __syncthreads();
  }

#pragma unroll
  for (int j = 0; j < 2; ++j) {
    float l = li[j];
    l += __shfl_xor(l, 16);
    l += __shfl_xor(l, 32);
    const float rl = 1.0f / l;
    const int qj = qb + j * 16 + l15;
    u16* mp = mix + ((size_t)b * NS + qj) * ND + h * DHD + quad * 4;
#pragma unroll
    for (int g = 0; g < 4; ++g) {
      ushort4v o;
#pragma unroll
      for (int r = 0; r < 4; ++r) o[r] = f2bf(O[j][g][r] * rl);
      *(ushort4v*)(mp + g * 16) = o;
    }
  }
}

// ---------------------------------------------------------------------------
// Kernel 3: out projection, fp32 output to (S,B,D). 2-phase + XCD swizzle
// (unchanged from R9 for attribution).
// ---------------------------------------------------------------------------
#define GEMM_STAGE(buf, k0)                                                  \
  do {                                                                       \
    GLD16(ga0 + (k0), &buf##A[c0 * 16][0]);                                  \
    GLD16(ga1 + (k0), &buf##A[c0 * 16 + 16][0]);                             \
    GLD16(gb0 + (k0), &buf##B[c0 * 16][0]);                                  \
    GLD16(gb1 + (k0), &buf##B[c0 * 16 + 16][0]);                             \
  } while (0)

#define GEMM_COMPUTE(buf)                                                    \
  do {                                                                       \
    short8 af[4], bfr[4];                                                    \
    _Pragma("unroll")                                                        \
    for (int mt = 0; mt < 4; ++mt)                                           \
      af[mt] = *(const short8*)&buf##A[wm * 64 + mt * 16 + l15][quad * 8];   \
    _Pragma("unroll")                                                        \
    for (int nt = 0; nt < 4; ++nt)                                           \
      bfr[nt] = *(const short8*)&buf##B[wn * 64 + nt * 16 + l15][quad * 8];  \
    _Pragma("unroll")                                                        \
    for (int mt = 0; mt < 4; ++mt)                                           \
      _Pragma("unroll")                                                      \
      for (int nt = 0; nt < 4; ++nt)                                         \
        acc[mt][nt] = __builtin_amdgcn_mfma_f32_16x16x32_bf16(               \
            af[mt], bfr[nt], acc[mt][nt], 0, 0, 0);                          \
  } while (0)

__global__ __launch_bounds__(256) void out_gemm(
    const u16* __restrict__ A, const u16* __restrict__ Wb,
    const float* __restrict__ bias, float* __restrict__ out) {
  __shared__ __align__(16) u16 p0A[128][32];
  __shared__ __align__(16) u16 p0B[128][32];
  __shared__ __align__(16) u16 p1A[128][32];
  __shared__ __align__(16) u16 p1B[128][32];
  const int tid = threadIdx.x;
  const int lane = tid & 63, wave = tid >> 6;
  const int l15 = lane & 15, quad = lane >> 4;
  const int wm = wave & 1, wn = wave >> 1;
  // XCD swizzle: L in [0,384). xcd=L&7, i=L>>3 in [0,48):
  // m = xcd+8*(i&7), n = i>>3 in [0,6). Bijective.
  const int L = (int)blockIdx.x + 64 * (int)blockIdx.y;
  const int xcd = L & 7, i = L >> 3;
  const int mblk = (xcd + 8 * (i & 7)) * 128;
  const int nblk = (i >> 3) * 128;

  floatx4 acc[4][4];
#pragma unroll
  for (int i2 = 0; i2 < 4; ++i2)
#pragma unroll
    for (int j = 0; j < 4; ++j) acc[i2][j] = (floatx4)0.f;

  const int lr = lane >> 2;
  const int lc = (lane & 3) * 8;
  const int c0 = wave * 2;
  const int r0 = c0 * 16 + lr, r1 = r0 + 16;
  const u16* ga0 = A + (mblk + r0) * ND + lc;
  const u16* ga1 = A + (mblk + r1) * ND + lc;
  const u16* gb0 = Wb + (nblk + r0) * ND + lc;
  const u16* gb1 = Wb + (nblk + r1) * ND + lc;

  GEMM_STAGE(p0, 0);
  __syncthreads();
  for (int kt = 0; kt < 24; kt += 2) {
    GEMM_STAGE(p1, (kt + 1) * 32);
    GEMM_COMPUTE(p0);
    __syncthreads();
    if (kt + 2 < 24) GEMM_STAGE(p0, (kt + 2) * 32);
    GEMM_COMPUTE(p1);
    __syncthreads();
  }

#pragma unroll
  for (int mt = 0; mt < 4; ++mt) {
#pragma unroll
    for (int r = 0; r < 4; ++r) {
      const int gm = mblk + wm * 64 + mt * 16 + quad * 4 + r;
      const int b = gm >> 10, s = gm & 1023;
#pragma unroll
      for (int nt = 0; nt < 4; ++nt) {
        const int gn = nblk + wn * 64 + nt * 16 + l15;
        out[(s * NB + b) * ND + gn] = acc[mt][nt][r] + bias[gn];
      }
    }
  }
}

extern "C" void kernel_launch(void* const* d_in, const int* in_sizes, int n_in,
                              void* d_out, int out_size, void* d_ws, size_t ws_size,
                              hipStream_t stream) {
  const float* X  = (const float*)d_in[0];
  const float* W  = (const float*)d_in[1];
  const float* Bi = (const float*)d_in[2];
  const float* Ow = (const float*)d_in[3];
  const float* Ob = (const float*)d_in[4];
  float* out = (float*)d_out;   // [q | k | v | out], each S*B*D fp32

  u16* Xb  = (u16*)d_ws;            // 6291456
  u16* Wb  = Xb  + 6291456;         // 1769472
  u16* Owb = Wb  + 1769472;         // 589824
  u16* Vt  = Owb + 589824;          // 6291456  (b,h,c,s)
  u16* Kb  = Vt  + 6291456;         // 6291456  (b,h,s,c)
  u16* mix = Kb  + 6291456;         // 6291456  (b,s,d)

  cvt3<<<CVT_B0 + CVT_B1 + CVT_B2, 256, 0, stream>>>(X, Xb, W, Wb, Ow, Owb);
  qkv_gemm<<<dim3(18, 32), 512, 0, stream>>>(Xb, Wb, Bi, out);
  prep<<<dim3(32, 96, 2), 256, 0, stream>>>(out + QKV_OUT_STRIDE,
                                            out + 2 * QKV_OUT_STRIDE, Kb, Vt);
  attn<<<dim3(8, 96), 256, 0, stream>>>(out, Kb, Vt, mix);
  out_gemm<<<dim3(64, 6), 256, 0, stream>>>(mix, Owb, Ob, out + 3 * QKV_OUT_STRIDE);
}

// Round 7
// 244.943 us; speedup vs baseline: 1.0097x; 1.0097x over previous
//
#include <hip/hip_runtime.h>
#include <hip/hip_bf16.h>

// S=1024, B=8, D=768, H=12, DH=64, PROMPT_NUM=8 (tokens=1016). I/O fp32.
// bf16 MFMA compute, fp32 accum. Attention: S^T = K*Q^T so the QK accumulator
// (row=key, col=q) IS the B-fragment of the 16x16x16 PV MFMA (P stays in
// registers). K/V tiles staged cooperatively in LDS, reg-buffered prefetch.
// R6: GEMM staging = m97 recipe (global_load_lds width=16, linear LDS).
// R7: attn P-pack via v_cvt_pk_bf16_f32; attn grid XCD-swizzle.
// R8: GEMM 2-phase LDS double-buffer.
// R9: GEMM XCD swizzle (best measured qkv config: 59.8 us, FETCH 32 MB).
// R10: 256x128 qkv tile REGRESSED (64.4 us, FETCH 64 MB) -> reverted to R9.
// R12: attn VALU cuts (attn is VALU-bound: 45% VALUBusy == ~26 us of softmax
//     VALU at 100M entries):
//     (a) Q pre-scaled by log2e/8 at load; softmax shift-invariance cancels
//         the 2^C0 factor between O and li -> p = exp2(a) directly (deletes
//         4 fmaf per (sub,j)).
//     (b) li accumulated via ones-A mfma16 (every output row = sum_k p[k][q])
//         -> deletes 3 VALU adds per (sub,j) + the final shfl reduce; work
//         moves to the half-idle MFMA pipe.
// NOTE: MFMA16/GLD16 gated on __HIP_DEVICE_COMPILE__ — the host pass's
// __has_builtin() returns false for amdgcn builtins (R4 compile failure).

typedef unsigned short u16;
typedef __attribute__((ext_vector_type(8))) short short8;    // 8 bf16 (K=32 frag)
typedef __attribute__((ext_vector_type(4))) short short4v;   // 4 bf16 (K=16 frag)
typedef __attribute__((ext_vector_type(4))) float floatx4;   // MFMA C/D frag
typedef __attribute__((ext_vector_type(4))) unsigned short ushort4v;
typedef __attribute__((ext_vector_type(2))) unsigned int uint2v;

#define NB 8
#define NS 1024
#define NH 12
#define ND 768
#define DHD 64
#define TOKENS 1016
#define QKV_OUT_STRIDE 6291456  // S*B*D elements per output tensor

#if __has_builtin(__builtin_amdgcn_exp2f)
#define EXP2(x) __builtin_amdgcn_exp2f(x)
#else
#define EXP2(x) exp2f(x)
#endif

#if defined(__HIP_DEVICE_COMPILE__)
  #if __has_builtin(__builtin_amdgcn_mfma_f32_16x16x16bf16_1k)
    #define MFMA16(a, b, c) __builtin_amdgcn_mfma_f32_16x16x16bf16_1k(a, b, c, 0, 0, 0)
  #else
    #define MFMA16(a, b, c) __builtin_amdgcn_mfma_f32_16x16x16_bf16(a, b, c, 0, 0, 0)
  #endif
  // async global->LDS, 16B per lane; LDS dest = wave-uniform base + lane*16.
  #define GLD16(g, l)                                                        \
    __builtin_amdgcn_global_load_lds(                                        \
        (const __attribute__((address_space(1))) void*)(g),                  \
        (__attribute__((address_space(3))) void*)(l), 16, 0, 0)
#else
  #define MFMA16(a, b, c) (c)   // host pass: dead code, never executed
  #define GLD16(g, l) ((void)0)
#endif

__device__ __forceinline__ u16 f2bf(float f) {
  union { float f; unsigned u; } c; c.f = f;
  return (u16)((c.u + 0x7fffu + ((c.u >> 16) & 1u)) >> 16);  // RNE
}

// ---------------------------------------------------------------------------
// Kernel 0: fp32 -> bf16 for X, in_proj_weight, out_w. 4 elems/thread.
// ---------------------------------------------------------------------------
#define CVT_B0 6144   // X:  6291456/1024
#define CVT_B1 1728   // W:  1769472/1024
#define CVT_B2 576    // Ow: 589824/1024
__global__ __launch_bounds__(256) void cvt3(
    const float* __restrict__ s0, u16* __restrict__ d0,
    const float* __restrict__ s1, u16* __restrict__ d1,
    const float* __restrict__ s2, u16* __restrict__ d2) {
  int blk = blockIdx.x;
  const float* s; u16* d;
  if (blk < CVT_B0) { s = s0; d = d0; }
  else if (blk < CVT_B0 + CVT_B1) { s = s1; d = d1; blk -= CVT_B0; }
  else { s = s2; d = d2; blk -= CVT_B0 + CVT_B1; }
  const int i = (blk * 256 + (int)threadIdx.x) * 4;
  const float4 v = *(const float4*)(s + i);
  ushort4v o;
  o.x = f2bf(v.x); o.y = f2bf(v.y); o.z = f2bf(v.z); o.w = f2bf(v.w);
  *(ushort4v*)(d + i) = o;
}

// ---------------------------------------------------------------------------
// Kernel 1: QKV projection. 128x128 tile/WG, 4 waves, 4x4 of 16x16x32 MFMA.
// 2-phase pipeline (R8) + XCD-swizzled block mapping (R9).
// ---------------------------------------------------------------------------
#define GEMM_STAGE(buf, k0)                                                  \
  do {                                                                       \
    GLD16(ga0 + (k0), &buf##A[c0 * 16][0]);                                  \
    GLD16(ga1 + (k0), &buf##A[c0 * 16 + 16][0]);                             \
    GLD16(gb0 + (k0), &buf##B[c0 * 16][0]);                                  \
    GLD16(gb1 + (k0), &buf##B[c0 * 16 + 16][0]);                             \
  } while (0)

#define GEMM_COMPUTE(buf)                                                    \
  do {                                                                       \
    short8 af[4], bfr[4];                                                    \
    _Pragma("unroll")                                                        \
    for (int mt = 0; mt < 4; ++mt)                                           \
      af[mt] = *(const short8*)&buf##A[wm * 64 + mt * 16 + l15][quad * 8];   \
    _Pragma("unroll")                                                        \
    for (int nt = 0; nt < 4; ++nt)                                           \
      bfr[nt] = *(const short8*)&buf##B[wn * 64 + nt * 16 + l15][quad * 8];  \
    _Pragma("unroll")                                                        \
    for (int mt = 0; mt < 4; ++mt)                                           \
      _Pragma("unroll")                                                      \
      for (int nt = 0; nt < 4; ++nt)                                         \
        acc[mt][nt] = __builtin_amdgcn_mfma_f32_16x16x32_bf16(               \
            af[mt], bfr[nt], acc[mt][nt], 0, 0, 0);                          \
  } while (0)

__global__ __launch_bounds__(256) void qkv_gemm(
    const u16* __restrict__ Xb, const u16* __restrict__ Wb,
    const float* __restrict__ bias, float* __restrict__ out) {
  __shared__ __align__(16) u16 p0A[128][32];
  __shared__ __align__(16) u16 p0B[128][32];
  __shared__ __align__(16) u16 p1A[128][32];
  __shared__ __align__(16) u16 p1B[128][32];
  const int tid = threadIdx.x;
  const int lane = tid & 63, wave = tid >> 6;
  const int l15 = lane & 15, quad = lane >> 4;
  const int wm = wave & 1, wn = wave >> 1;
  // XCD swizzle: L in [0,1152). xcd=L&7 -> m-set {xcd,xcd+8,..,xcd+56}
  // (1.5 MB X-slice, L2-resident all kernel); n advances every 8 WGs.
  const int L = (int)blockIdx.x + 64 * (int)blockIdx.y;
  const int xcd = L & 7, i = L >> 3;
  const int mblk = (xcd + 8 * (i & 7)) * 128;
  const int nblk = (i >> 3) * 128;

  floatx4 acc[4][4];
#pragma unroll
  for (int i2 = 0; i2 < 4; ++i2)
#pragma unroll
    for (int j = 0; j < 4; ++j) acc[i2][j] = (floatx4)0.f;

  // staging geometry (per wave: row-chunks c0, c0+1 of A and of B)
  const int lr = lane >> 2;
  const int lc = (lane & 3) * 8;
  const int c0 = wave * 2;
  const int r0 = c0 * 16 + lr, r1 = r0 + 16;
  const int gm0 = mblk + r0, gm1 = mblk + r1;
  // X is (S,B,D): row gm -> b=gm>>10, s=gm&1023
  const u16* ga0 = Xb + ((gm0 & 1023) * NB + (gm0 >> 10)) * ND + lc;
  const u16* ga1 = Xb + ((gm1 & 1023) * NB + (gm1 >> 10)) * ND + lc;
  const u16* gb0 = Wb + (nblk + r0) * ND + lc;
  const u16* gb1 = Wb + (nblk + r1) * ND + lc;

  GEMM_STAGE(p0, 0);
  __syncthreads();
  for (int kt = 0; kt < 24; kt += 2) {
    // phase A: prefetch tile kt+1 into p1, compute p0 (kt+1 <= 23 always)
    GEMM_STAGE(p1, (kt + 1) * 32);
    GEMM_COMPUTE(p0);
    __syncthreads();   // drains vmcnt(0): p1 ready; p0 reads fenced
    // phase B: prefetch tile kt+2 into p0, compute p1
    if (kt + 2 < 24) GEMM_STAGE(p0, (kt + 2) * 32);
    GEMM_COMPUTE(p1);
    __syncthreads();
  }

#pragma unroll
  for (int mt = 0; mt < 4; ++mt) {
#pragma unroll
    for (int r = 0; r < 4; ++r) {
      const int gm = mblk + wm * 64 + mt * 16 + quad * 4 + r;
      const int b = gm >> 10, s = gm & 1023;
#pragma unroll
      for (int nt = 0; nt < 4; ++nt) {
        const int gn = nblk + wn * 64 + nt * 16 + l15;
        const int seg = gn / ND;
        const int nn = gn - seg * ND;
        out[seg * QKV_OUT_STRIDE + (s * NB + b) * ND + nn] = acc[mt][nt][r] + bias[gn];
      }
    }
  }
}

// ---------------------------------------------------------------------------
// Kernel 1b: prep. z=0: K fp32 -> Kb[b,h,s,c] bf16. z=1: V -> Vt[b,h,c,s].
// ---------------------------------------------------------------------------
__global__ __launch_bounds__(256) void prep(
    const float* __restrict__ K, const float* __restrict__ V,
    u16* __restrict__ Kb, u16* __restrict__ Vt) {
  __shared__ u16 tile[DHD][40];
  const int t = threadIdx.x;
  const int bh = blockIdx.y;
  const int b = bh / NH, h = bh % NH;
  const int s0 = blockIdx.x * 32;
  const int sl = t >> 3;
  const int c0 = (t & 7) * 8;
  const int s = s0 + sl;
  if (blockIdx.z == 0) {
    const float* src = K + ((s * NB + b) * NH + h) * DHD + c0;
    const float4 v0 = *(const float4*)src;
    const float4 v1 = *(const float4*)(src + 4);
    short8 o;
    o[0] = f2bf(v0.x); o[1] = f2bf(v0.y); o[2] = f2bf(v0.z); o[3] = f2bf(v0.w);
    o[4] = f2bf(v1.x); o[5] = f2bf(v1.y); o[6] = f2bf(v1.z); o[7] = f2bf(v1.w);
    *(short8*)(Kb + ((size_t)bh * NS + s) * DHD + c0) = o;
  } else {
    const float* src = V + ((s * NB + b) * NH + h) * DHD + c0;
    const float4 v0 = *(const float4*)src;
    const float4 v1 = *(const float4*)(src + 4);
    tile[c0 + 0][sl] = f2bf(v0.x); tile[c0 + 1][sl] = f2bf(v0.y);
    tile[c0 + 2][sl] = f2bf(v0.z); tile[c0 + 3][sl] = f2bf(v0.w);
    tile[c0 + 4][sl] = f2bf(v1.x); tile[c0 + 5][sl] = f2bf(v1.y);
    tile[c0 + 6][sl] = f2bf(v1.z); tile[c0 + 7][sl] = f2bf(v1.w);
    __syncthreads();
    const int c = t >> 2;
    const int so = (t & 3) * 8;
    *(short8*)(Vt + ((size_t)bh * DHD + c) * NS + s0 + so) =
        *(const short8*)&tile[c][so];
  }
}

// ---------------------------------------------------------------------------
// Kernel 2: flash attention. WG = 128 q of one (b,h); wave = 32 q (2 Q frags).
// 16 outer iters of 64-key tiles staged in LDS (reg-buffered prefetch).
// Register-only P path (Q pre-scaled by log2e/8; shift-invariance cancels
// the exp bias):
//   S'^T = mfma32(K-frag, Qs-frag)   (C row=key, col=q; already log2-scaled)
//   p = exp2(s'); pack via v_cvt_pk_bf16_f32 -> B-frag of 16x16x16
//   O^T[g] = mfma16(V-frag, p, O^T[g]);  li = mfma16(ones, p, li)
// Grid is XCD-swizzled: all 8 q-blocks of one (b,h) on one XCD.
// ---------------------------------------------------------------------------
__global__ __launch_bounds__(256) void attn(
    const float* __restrict__ Q, const u16* __restrict__ Kb,
    const u16* __restrict__ Vt, u16* __restrict__ mix) {
  __shared__ __align__(16) u16 Kt[64][72];  // [key_local][c]
  __shared__ __align__(16) u16 Vs[64][72];  // [c][key_local]
  const int tid = threadIdx.x;
  const int lane = tid & 63, wave = tid >> 6;
  const int l15 = lane & 15, quad = lane >> 4;
  // XCD swizzle: L in [0,768). xcd = L&7, t = L>>3 in [0,96).
  // bh = xcd + 8*(t>>3)  (12 bh per XCD), qx = t&7. Bijective.
  const int L = (int)blockIdx.x + 8 * (int)blockIdx.y;
  const int xcd = L & 7, tt = L >> 3;
  const int bh = xcd + 8 * (tt >> 3);
  const int qx = tt & 7;
  const int b = bh / NH, h = bh % NH;
  const int qb = qx * 128 + wave * 32;

  const float SC = 0.125f * 1.44269504089f;    // 1/sqrt(64) * log2(e)

  // Q B-frags: n=l15 -> q, k=quad*8+j -> channel. fp32 -> bf16 once,
  // pre-scaled so the QK MFMA output is already in log2 space.
  short8 qf[2][2];
  bool qmask[2];
#pragma unroll
  for (int j = 0; j < 2; ++j) {
    const int qj = qb + j * 16 + l15;
    qmask[j] = (qj == 0 || qj >= TOKENS);
    const float* qp = Q + ((qj * NB + b) * NH + h) * DHD + quad * 8;
#pragma unroll
    for (int e = 0; e < 8; ++e) {
      qf[j][0][e] = (short)f2bf(qp[e] * SC);
      qf[j][1][e] = (short)f2bf(qp[32 + e] * SC);
    }
  }

  floatx4 O[2][4];
#pragma unroll
  for (int j = 0; j < 2; ++j)
#pragma unroll
    for (int g = 0; g < 4; ++g) O[j][g] = (floatx4)0.f;
  floatx4 liacc[2];
  liacc[0] = (floatx4)0.f;
  liacc[1] = (floatx4)0.f;
  short4v ones4;
#pragma unroll
  for (int e = 0; e < 4; ++e) ones4[e] = (short)0x3F80;  // bf16 1.0

  const u16* kg = Kb + (size_t)bh * NS * DHD;  // rows of 64 shorts (s,c)
  const u16* vg = Vt + (size_t)bh * DHD * NS;  // rows of 1024 shorts (c,s)

  // staging: thread t covers row t>>2 (0..63), 32B chunk (t&3)*16 shorts
  const int srow = tid >> 2;
  const int scol = (tid & 3) * 16;

  short8 pk0, pk1, pv0, pv1;
  {
    pk0 = *(const short8*)(kg + srow * DHD + scol);
    pk1 = *(const short8*)(kg + srow * DHD + scol + 8);
    pv0 = *(const short8*)(vg + srow * NS + scol);
    pv1 = *(const short8*)(vg + srow * NS + scol + 8);
  }

  for (int it = 0; it < 16; ++it) {
    *(short8*)&Kt[srow][scol] = pk0;
    *(short8*)&Kt[srow][scol + 8] = pk1;
    *(short8*)&Vs[srow][scol] = pv0;
    *(short8*)&Vs[srow][scol + 8] = pv1;
    __syncthreads();
    if (it < 15) {
      const int k0 = (it + 1) * 64;
      pk0 = *(const short8*)(kg + (k0 + srow) * DHD + scol);
      pk1 = *(const short8*)(kg + (k0 + srow) * DHD + scol + 8);
      pv0 = *(const short8*)(vg + srow * NS + k0 + scol);
      pv1 = *(const short8*)(vg + srow * NS + k0 + scol + 8);
    }
    const bool mrow = (it == 15) && (quad >= 2);  // keys >= 1016 rows
#pragma unroll
    for (int sub = 0; sub < 4; ++sub) {
      const short8 kf0 = *(const short8*)&Kt[sub * 16 + l15][quad * 8];
      const short8 kf1 = *(const short8*)&Kt[sub * 16 + l15][32 + quad * 8];
      short4v pb[2];
#pragma unroll
      for (int j = 0; j < 2; ++j) {
        floatx4 a = (floatx4)0.f;
        a = __builtin_amdgcn_mfma_f32_16x16x32_bf16(kf0, qf[j][0], a, 0, 0, 0);
        a = __builtin_amdgcn_mfma_f32_16x16x32_bf16(kf1, qf[j][1], a, 0, 0, 0);
        float p[4];
#pragma unroll
        for (int r = 0; r < 4; ++r) p[r] = EXP2(a[r]);
        if (sub == 3 && mrow && qmask[j]) {
#pragma unroll
          for (int r = 0; r < 4; ++r) p[r] = 0.f;
        }
        // pack 4 fp32 -> 4 bf16 via v_cvt_pk_bf16_f32 (RNE, same as f2bf)
        __hip_bfloat162 w0 = __float22bfloat162_rn(make_float2(p[0], p[1]));
        __hip_bfloat162 w1 = __float22bfloat162_rn(make_float2(p[2], p[3]));
        uint2v pw;
        pw.x = *(const unsigned*)&w0;
        pw.y = *(const unsigned*)&w1;
        pb[j] = __builtin_bit_cast(short4v, pw);
      }
#pragma unroll
      for (int g = 0; g < 4; ++g) {
        const short4v vf = *(const short4v*)&Vs[g * 16 + l15][sub * 16 + quad * 4];
        O[0][g] = MFMA16(vf, pb[0], O[0][g]);
        O[1][g] = MFMA16(vf, pb[1], O[1][g]);
      }
      // li on the MFMA pipe: every output row of ones-A mfma = sum_k p[k][q]
      liacc[0] = MFMA16(ones4, pb[0], liacc[0]);
      liacc[1] = MFMA16(ones4, pb[1], liacc[1]);
    }
    __syncthreads();
  }

#pragma unroll
  for (int j = 0; j < 2; ++j) {
    const float rl = 1.0f / liacc[j][0];  // all rows/quads hold the full sum
    const int qj = qb + j * 16 + l15;
    u16* mp = mix + ((size_t)b * NS + qj) * ND + h * DHD + quad * 4;
#pragma unroll
    for (int g = 0; g < 4; ++g) {
      ushort4v o;
#pragma unroll
      for (int r = 0; r < 4; ++r) o[r] = f2bf(O[j][g][r] * rl);
      *(ushort4v*)(mp + g * 16) = o;
    }
  }
}

// ---------------------------------------------------------------------------
// Kernel 3: out projection, fp32 output to (S,B,D). 2-phase + XCD swizzle.
// ---------------------------------------------------------------------------
__global__ __launch_bounds__(256) void out_gemm(
    const u16* __restrict__ A, const u16* __restrict__ Wb,
    const float* __restrict__ bias, float* __restrict__ out) {
  __shared__ __align__(16) u16 p0A[128][32];
  __shared__ __align__(16) u16 p0B[128][32];
  __shared__ __align__(16) u16 p1A[128][32];
  __shared__ __align__(16) u16 p1B[128][32];
  const int tid = threadIdx.x;
  const int lane = tid & 63, wave = tid >> 6;
  const int l15 = lane & 15, quad = lane >> 4;
  const int wm = wave & 1, wn = wave >> 1;
  // XCD swizzle: L in [0,384). xcd=L&7, i=L>>3 in [0,48):
  // m = xcd+8*(i&7), n = i>>3 in [0,6). Bijective.
  const int L = (int)blockIdx.x + 64 * (int)blockIdx.y;
  const int xcd = L & 7, i = L >> 3;
  const int mblk = (xcd + 8 * (i & 7)) * 128;
  const int nblk = (i >> 3) * 128;

  floatx4 acc[4][4];
#pragma unroll
  for (int i2 = 0; i2 < 4; ++i2)
#pragma unroll
    for (int j = 0; j < 4; ++j) acc[i2][j] = (floatx4)0.f;

  const int lr = lane >> 2;
  const int lc = (lane & 3) * 8;
  const int c0 = wave * 2;
  const int r0 = c0 * 16 + lr, r1 = r0 + 16;
  const u16* ga0 = A + (mblk + r0) * ND + lc;
  const u16* ga1 = A + (mblk + r1) * ND + lc;
  const u16* gb0 = Wb + (nblk + r0) * ND + lc;
  const u16* gb1 = Wb + (nblk + r1) * ND + lc;

  GEMM_STAGE(p0, 0);
  __syncthreads();
  for (int kt = 0; kt < 24; kt += 2) {
    GEMM_STAGE(p1, (kt + 1) * 32);
    GEMM_COMPUTE(p0);
    __syncthreads();
    if (kt + 2 < 24) GEMM_STAGE(p0, (kt + 2) * 32);
    GEMM_COMPUTE(p1);
    __syncthreads();
  }

#pragma unroll
  for (int mt = 0; mt < 4; ++mt) {
#pragma unroll
    for (int r = 0; r < 4; ++r) {
      const int gm = mblk + wm * 64 + mt * 16 + quad * 4 + r;
      const int b = gm >> 10, s = gm & 1023;
#pragma unroll
      for (int nt = 0; nt < 4; ++nt) {
        const int gn = nblk + wn * 64 + nt * 16 + l15;
        out[(s * NB + b) * ND + gn] = acc[mt][nt][r] + bias[gn];
      }
    }
  }
}

extern "C" void kernel_launch(void* const* d_in, const int* in_sizes, int n_in,
                              void* d_out, int out_size, void* d_ws, size_t ws_size,
                              hipStream_t stream) {
  const float* X  = (const float*)d_in[0];
  const float* W  = (const float*)d_in[1];
  const float* Bi = (const float*)d_in[2];
  const float* Ow = (const float*)d_in[3];
  const float* Ob = (const float*)d_in[4];
  float* out = (float*)d_out;   // [q | k | v | out], each S*B*D fp32

  u16* Xb  = (u16*)d_ws;            // 6291456
  u16* Wb  = Xb  + 6291456;         // 1769472
  u16* Owb = Wb  + 1769472;         // 589824
  u16* Vt  = Owb + 589824;          // 6291456  (b,h,c,s)
  u16* Kb  = Vt  + 6291456;         // 6291456  (b,h,s,c)
  u16* mix = Kb  + 6291456;         // 6291456  (b,s,d)

  cvt3<<<CVT_B0 + CVT_B1 + CVT_B2, 256, 0, stream>>>(X, Xb, W, Wb, Ow, Owb);
  qkv_gemm<<<dim3(64, 18), 256, 0, stream>>>(Xb, Wb, Bi, out);
  prep<<<dim3(32, 96, 2), 256, 0, stream>>>(out + QKV_OUT_STRIDE,
                                            out + 2 * QKV_OUT_STRIDE, Kb, Vt);
  attn<<<dim3(8, 96), 256, 0, stream>>>(out, Kb, Vt, mix);
  out_gemm<<<dim3(64, 6), 256, 0, stream>>>(mix, Owb, Ob, out + 3 * QKV_OUT_STRIDE);
}

// Round 9
// 235.642 us; speedup vs baseline: 1.0496x; 1.0395x over previous
//
#include <hip/hip_runtime.h>
#include <hip/hip_bf16.h>

// S=1024, B=8, D=768, H=12, DH=64, PROMPT_NUM=8 (tokens=1016). I/O fp32.
// bf16 MFMA compute, fp32 accum. Attention: S^T = K*Q^T so the QK accumulator
// (row=key, col=q) IS the B-fragment of the 16x16x16 PV MFMA (P stays in
// registers). K/V tiles staged cooperatively in LDS, reg-buffered prefetch.
// R6: GEMM staging = m97 recipe (global_load_lds width=16, linear LDS).
// R7: attn P-pack via v_cvt_pk_bf16_f32; attn grid XCD-swizzle.
// R8: GEMM 2-phase LDS double-buffer. R9: GEMM XCD swizzle.
// R12: attn softmax on exp2-domain Q prescale + ones-MFMA li (verified).
// R13: Xb stored m-major dense (m = b*1024+s) by cvt3. Evidence: out_gemm
//     (identical structure, dense A) runs ~2400 cyc/K-iter = m97 floor;
//     qkv runs 6400 cyc/iter. qkv's A rows were 12 KB apart through the
//     (s,b,d) interleave -> every staging op gathered 16 scattered 64B
//     lines. Dense A makes qkv's staging identical to out_gemm's.
//     Also: epilogue seg (gn/768) hoisted to block-uniform constant.
// R14: identical resubmit of R13 — bench died to container-infra failure
//     (same signature as R5/round-1; kernel never measured).
// NOTE: MFMA16/GLD16 gated on __HIP_DEVICE_COMPILE__ — the host pass's
// __has_builtin() returns false for amdgcn builtins (R4 compile failure).

typedef unsigned short u16;
typedef __attribute__((ext_vector_type(8))) short short8;    // 8 bf16 (K=32 frag)
typedef __attribute__((ext_vector_type(4))) short short4v;   // 4 bf16 (K=16 frag)
typedef __attribute__((ext_vector_type(4))) float floatx4;   // MFMA C/D frag
typedef __attribute__((ext_vector_type(4))) unsigned short ushort4v;
typedef __attribute__((ext_vector_type(2))) unsigned int uint2v;

#define NB 8
#define NS 1024
#define NH 12
#define ND 768
#define DHD 64
#define TOKENS 1016
#define QKV_OUT_STRIDE 6291456  // S*B*D elements per output tensor

#if __has_builtin(__builtin_amdgcn_exp2f)
#define EXP2(x) __builtin_amdgcn_exp2f(x)
#else
#define EXP2(x) exp2f(x)
#endif

#if defined(__HIP_DEVICE_COMPILE__)
  #if __has_builtin(__builtin_amdgcn_mfma_f32_16x16x16bf16_1k)
    #define MFMA16(a, b, c) __builtin_amdgcn_mfma_f32_16x16x16bf16_1k(a, b, c, 0, 0, 0)
  #else
    #define MFMA16(a, b, c) __builtin_amdgcn_mfma_f32_16x16x16_bf16(a, b, c, 0, 0, 0)
  #endif
  // async global->LDS, 16B per lane; LDS dest = wave-uniform base + lane*16.
  #define GLD16(g, l)                                                        \
    __builtin_amdgcn_global_load_lds(                                        \
        (const __attribute__((address_space(1))) void*)(g),                  \
        (__attribute__((address_space(3))) void*)(l), 16, 0, 0)
#else
  #define MFMA16(a, b, c) (c)   // host pass: dead code, never executed
  #define GLD16(g, l) ((void)0)
#endif

__device__ __forceinline__ u16 f2bf(float f) {
  union { float f; unsigned u; } c; c.f = f;
  return (u16)((c.u + 0x7fffu + ((c.u >> 16) & 1u)) >> 16);  // RNE
}

// ---------------------------------------------------------------------------
// Kernel 0: fp32 -> bf16 for X, in_proj_weight, out_w. 4 elems/thread.
// X is additionally permuted to m-major dense rows: m = b*1024 + s.
// ---------------------------------------------------------------------------
#define CVT_B0 6144   // X:  6291456/1024
#define CVT_B1 1728   // W:  1769472/1024
#define CVT_B2 576    // Ow: 589824/1024
__global__ __launch_bounds__(256) void cvt3(
    const float* __restrict__ s0, u16* __restrict__ d0,
    const float* __restrict__ s1, u16* __restrict__ d1,
    const float* __restrict__ s2, u16* __restrict__ d2) {
  int blk = blockIdx.x;
  if (blk < CVT_B0) {
    // X: read (s,b,d) flat, write row m = b*1024+s dense.
    const int i = (blk * 256 + (int)threadIdx.x) * 4;
    const float4 v = *(const float4*)(s0 + i);
    const int sb = i / ND;            // s*8 + b
    const int dd = i - sb * ND;       // 4-aligned, stays in-row (4 | 768)
    const int m = ((sb & 7) << 10) | (sb >> 3);
    ushort4v o;
    o.x = f2bf(v.x); o.y = f2bf(v.y); o.z = f2bf(v.z); o.w = f2bf(v.w);
    *(ushort4v*)(d0 + m * ND + dd) = o;
    return;
  }
  const float* s; u16* d;
  if (blk < CVT_B0 + CVT_B1) { s = s1; d = d1; blk -= CVT_B0; }
  else { s = s2; d = d2; blk -= CVT_B0 + CVT_B1; }
  const int i = (blk * 256 + (int)threadIdx.x) * 4;
  const float4 v = *(const float4*)(s + i);
  ushort4v o;
  o.x = f2bf(v.x); o.y = f2bf(v.y); o.z = f2bf(v.z); o.w = f2bf(v.w);
  *(ushort4v*)(d + i) = o;
}

// ---------------------------------------------------------------------------
// Kernel 1: QKV projection. 128x128 tile/WG, 4 waves, 4x4 of 16x16x32 MFMA.
// 2-phase pipeline (R8) + XCD-swizzled block mapping (R9) + dense A (R13).
// ---------------------------------------------------------------------------
#define GEMM_STAGE(buf, k0)                                                  \
  do {                                                                       \
    GLD16(ga0 + (k0), &buf##A[c0 * 16][0]);                                  \
    GLD16(ga1 + (k0), &buf##A[c0 * 16 + 16][0]);                             \
    GLD16(gb0 + (k0), &buf##B[c0 * 16][0]);                                  \
    GLD16(gb1 + (k0), &buf##B[c0 * 16 + 16][0]);                             \
  } while (0)

#define GEMM_COMPUTE(buf)                                                    \
  do {                                                                       \
    short8 af[4], bfr[4];                                                    \
    _Pragma("unroll")                                                        \
    for (int mt = 0; mt < 4; ++mt)                                           \
      af[mt] = *(const short8*)&buf##A[wm * 64 + mt * 16 + l15][quad * 8];   \
    _Pragma("unroll")                                                        \
    for (int nt = 0; nt < 4; ++nt)                                           \
      bfr[nt] = *(const short8*)&buf##B[wn * 64 + nt * 16 + l15][quad * 8];  \
    _Pragma("unroll")                                                        \
    for (int mt = 0; mt < 4; ++mt)                                           \
      _Pragma("unroll")                                                      \
      for (int nt = 0; nt < 4; ++nt)                                         \
        acc[mt][nt] = __builtin_amdgcn_mfma_f32_16x16x32_bf16(               \
            af[mt], bfr[nt], acc[mt][nt], 0, 0, 0);                          \
  } while (0)

__global__ __launch_bounds__(256) void qkv_gemm(
    const u16* __restrict__ Xb, const u16* __restrict__ Wb,
    const float* __restrict__ bias, float* __restrict__ out) {
  __shared__ __align__(16) u16 p0A[128][32];
  __shared__ __align__(16) u16 p0B[128][32];
  __shared__ __align__(16) u16 p1A[128][32];
  __shared__ __align__(16) u16 p1B[128][32];
  const int tid = threadIdx.x;
  const int lane = tid & 63, wave = tid >> 6;
  const int l15 = lane & 15, quad = lane >> 4;
  const int wm = wave & 1, wn = wave >> 1;
  // XCD swizzle: L in [0,1152). xcd=L&7 -> m-set {xcd,xcd+8,..,xcd+56};
  // n advances every 8 WGs.
  const int L = (int)blockIdx.x + 64 * (int)blockIdx.y;
  const int xcd = L & 7, i = L >> 3;
  const int mblk = (xcd + 8 * (i & 7)) * 128;
  const int nblk = (i >> 3) * 128;

  floatx4 acc[4][4];
#pragma unroll
  for (int i2 = 0; i2 < 4; ++i2)
#pragma unroll
    for (int j = 0; j < 4; ++j) acc[i2][j] = (floatx4)0.f;

  // staging geometry (per wave: row-chunks c0, c0+1 of A and of B)
  const int lr = lane >> 2;
  const int lc = (lane & 3) * 8;
  const int c0 = wave * 2;
  const int r0 = c0 * 16 + lr, r1 = r0 + 16;
  // Xb is m-major dense: row gm at Xb + gm*ND (R13)
  const u16* ga0 = Xb + (mblk + r0) * ND + lc;
  const u16* ga1 = Xb + (mblk + r1) * ND + lc;
  const u16* gb0 = Wb + (nblk + r0) * ND + lc;
  const u16* gb1 = Wb + (nblk + r1) * ND + lc;

  GEMM_STAGE(p0, 0);
  __syncthreads();
  for (int kt = 0; kt < 24; kt += 2) {
    // phase A: prefetch tile kt+1 into p1, compute p0 (kt+1 <= 23 always)
    GEMM_STAGE(p1, (kt + 1) * 32);
    GEMM_COMPUTE(p0);
    __syncthreads();   // drains vmcnt(0): p1 ready; p0 reads fenced
    // phase B: prefetch tile kt+2 into p0, compute p1
    if (kt + 2 < 24) GEMM_STAGE(p0, (kt + 2) * 32);
    GEMM_COMPUTE(p1);
    __syncthreads();
  }

  // epilogue: seg is block-uniform (128 | 768 -> n-block within one segment)
  const int seg = nblk / ND;
  const int nbase = nblk - seg * ND;
  float* outp = out + seg * QKV_OUT_STRIDE;
#pragma unroll
  for (int mt = 0; mt < 4; ++mt) {
#pragma unroll
    for (int r = 0; r < 4; ++r) {
      const int gm = mblk + wm * 64 + mt * 16 + quad * 4 + r;
      const int b = gm >> 10, s = gm & 1023;
#pragma unroll
      for (int nt = 0; nt < 4; ++nt) {
        const int gn = nblk + wn * 64 + nt * 16 + l15;
        const int nn = nbase + wn * 64 + nt * 16 + l15;
        outp[(s * NB + b) * ND + nn] = acc[mt][nt][r] + bias[gn];
      }
    }
  }
}

// ---------------------------------------------------------------------------
// Kernel 1b: prep. z=0: K fp32 -> Kb[b,h,s,c] bf16. z=1: V -> Vt[b,h,c,s].
// ---------------------------------------------------------------------------
__global__ __launch_bounds__(256) void prep(
    const float* __restrict__ K, const float* __restrict__ V,
    u16* __restrict__ Kb, u16* __restrict__ Vt) {
  __shared__ u16 tile[DHD][40];
  const int t = threadIdx.x;
  const int bh = blockIdx.y;
  const int b = bh / NH, h = bh % NH;
  const int s0 = blockIdx.x * 32;
  const int sl = t >> 3;
  const int c0 = (t & 7) * 8;
  const int s = s0 + sl;
  if (blockIdx.z == 0) {
    const float* src = K + ((s * NB + b) * NH + h) * DHD + c0;
    const float4 v0 = *(const float4*)src;
    const float4 v1 = *(const float4*)(src + 4);
    short8 o;
    o[0] = f2bf(v0.x); o[1] = f2bf(v0.y); o[2] = f2bf(v0.z); o[3] = f2bf(v0.w);
    o[4] = f2bf(v1.x); o[5] = f2bf(v1.y); o[6] = f2bf(v1.z); o[7] = f2bf(v1.w);
    *(short8*)(Kb + ((size_t)bh * NS + s) * DHD + c0) = o;
  } else {
    const float* src = V + ((s * NB + b) * NH + h) * DHD + c0;
    const float4 v0 = *(const float4*)src;
    const float4 v1 = *(const float4*)(src + 4);
    tile[c0 + 0][sl] = f2bf(v0.x); tile[c0 + 1][sl] = f2bf(v0.y);
    tile[c0 + 2][sl] = f2bf(v0.z); tile[c0 + 3][sl] = f2bf(v0.w);
    tile[c0 + 4][sl] = f2bf(v1.x); tile[c0 + 5][sl] = f2bf(v1.y);
    tile[c0 + 6][sl] = f2bf(v1.z); tile[c0 + 7][sl] = f2bf(v1.w);
    __syncthreads();
    const int c = t >> 2;
    const int so = (t & 3) * 8;
    *(short8*)(Vt + ((size_t)bh * DHD + c) * NS + s0 + so) =
        *(const short8*)&tile[c][so];
  }
}

// ---------------------------------------------------------------------------
// Kernel 2: flash attention. WG = 128 q of one (b,h); wave = 32 q (2 Q frags).
// 16 outer iters of 64-key tiles staged in LDS (reg-buffered prefetch).
// Register-only P path (Q pre-scaled by log2e/8; shift-invariance cancels
// the exp bias):
//   S'^T = mfma32(K-frag, Qs-frag)   (C row=key, col=q; already log2-scaled)
//   p = exp2(s'); pack via v_cvt_pk_bf16_f32 -> B-frag of 16x16x16
//   O^T[g] = mfma16(V-frag, p, O^T[g]);  li = mfma16(ones, p, li)
// Grid is XCD-swizzled: all 8 q-blocks of one (b,h) on one XCD.
// ---------------------------------------------------------------------------
__global__ __launch_bounds__(256) void attn(
    const float* __restrict__ Q, const u16* __restrict__ Kb,
    const u16* __restrict__ Vt, u16* __restrict__ mix) {
  __shared__ __align__(16) u16 Kt[64][72];  // [key_local][c]
  __shared__ __align__(16) u16 Vs[64][72];  // [c][key_local]
  const int tid = threadIdx.x;
  const int lane = tid & 63, wave = tid >> 6;
  const int l15 = lane & 15, quad = lane >> 4;
  // XCD swizzle: L in [0,768). xcd = L&7, t = L>>3 in [0,96).
  // bh = xcd + 8*(t>>3)  (12 bh per XCD), qx = t&7. Bijective.
  const int L = (int)blockIdx.x + 8 * (int)blockIdx.y;
  const int xcd = L & 7, tt = L >> 3;
  const int bh = xcd + 8 * (tt >> 3);
  const int qx = tt & 7;
  const int b = bh / NH, h = bh % NH;
  const int qb = qx * 128 + wave * 32;

  const float SC = 0.125f * 1.44269504089f;    // 1/sqrt(64) * log2(e)

  // Q B-frags: n=l15 -> q, k=quad*8+j -> channel. fp32 -> bf16 once,
  // pre-scaled so the QK MFMA output is already in log2 space.
  short8 qf[2][2];
  bool qmask[2];
#pragma unroll
  for (int j = 0; j < 2; ++j) {
    const int qj = qb + j * 16 + l15;
    qmask[j] = (qj == 0 || qj >= TOKENS);
    const float* qp = Q + ((qj * NB + b) * NH + h) * DHD + quad * 8;
#pragma unroll
    for (int e = 0; e < 8; ++e) {
      qf[j][0][e] = (short)f2bf(qp[e] * SC);
      qf[j][1][e] = (short)f2bf(qp[32 + e] * SC);
    }
  }

  floatx4 O[2][4];
#pragma unroll
  for (int j = 0; j < 2; ++j)
#pragma unroll
    for (int g = 0; g < 4; ++g) O[j][g] = (floatx4)0.f;
  floatx4 liacc[2];
  liacc[0] = (floatx4)0.f;
  liacc[1] = (floatx4)0.f;
  short4v ones4;
#pragma unroll
  for (int e = 0; e < 4; ++e) ones4[e] = (short)0x3F80;  // bf16 1.0

  const u16* kg = Kb + (size_t)bh * NS * DHD;  // rows of 64 shorts (s,c)
  const u16* vg = Vt + (size_t)bh * DHD * NS;  // rows of 1024 shorts (c,s)

  // staging: thread t covers row t>>2 (0..63), 32B chunk (t&3)*16 shorts
  const int srow = tid >> 2;
  const int scol = (tid & 3) * 16;

  short8 pk0, pk1, pv0, pv1;
  {
    pk0 = *(const short8*)(kg + srow * DHD + scol);
    pk1 = *(const short8*)(kg + srow * DHD + scol + 8);
    pv0 = *(const short8*)(vg + srow * NS + scol);
    pv1 = *(const short8*)(vg + srow * NS + scol + 8);
  }

  for (int it = 0; it < 16; ++it) {
    *(short8*)&Kt[srow][scol] = pk0;
    *(short8*)&Kt[srow][scol + 8] = pk1;
    *(short8*)&Vs[srow][scol] = pv0;
    *(short8*)&Vs[srow][scol + 8] = pv1;
    __syncthreads();
    if (it < 15) {
      const int k0 = (it + 1) * 64;
      pk0 = *(const short8*)(kg + (k0 + srow) * DHD + scol);
      pk1 = *(const short8*)(kg + (k0 + srow) * DHD + scol + 8);
      pv0 = *(const short8*)(vg + srow * NS + k0 + scol);
      pv1 = *(const short8*)(vg + srow * NS + k0 + scol + 8);
    }
    const bool mrow = (it == 15) && (quad >= 2);  // keys >= 1016 rows
#pragma unroll
    for (int sub = 0; sub < 4; ++sub) {
      const short8 kf0 = *(const short8*)&Kt[sub * 16 + l15][quad * 8];
      const short8 kf1 = *(const short8*)&Kt[sub * 16 + l15][32 + quad * 8];
      short4v pb[2];
#pragma unroll
      for (int j = 0; j < 2; ++j) {
        floatx4 a = (floatx4)0.f;
        a = __builtin_amdgcn_mfma_f32_16x16x32_bf16(kf0, qf[j][0], a, 0, 0, 0);
        a = __builtin_amdgcn_mfma_f32_16x16x32_bf16(kf1, qf[j][1], a, 0, 0, 0);
        float p[4];
#pragma unroll
        for (int r = 0; r < 4; ++r) p[r] = EXP2(a[r]);
        if (sub == 3 && mrow && qmask[j]) {
#pragma unroll
          for (int r = 0; r < 4; ++r) p[r] = 0.f;
        }
        // pack 4 fp32 -> 4 bf16 via v_cvt_pk_bf16_f32 (RNE, same as f2bf)
        __hip_bfloat162 w0 = __float22bfloat162_rn(make_float2(p[0], p[1]));
        __hip_bfloat162 w1 = __float22bfloat162_rn(make_float2(p[2], p[3]));
        uint2v pw;
        pw.x = *(const unsigned*)&w0;
        pw.y = *(const unsigned*)&w1;
        pb[j] = __builtin_bit_cast(short4v, pw);
      }
#pragma unroll
      for (int g = 0; g < 4; ++g) {
        const short4v vf = *(const short4v*)&Vs[g * 16 + l15][sub * 16 + quad * 4];
        O[0][g] = MFMA16(vf, pb[0], O[0][g]);
        O[1][g] = MFMA16(vf, pb[1], O[1][g]);
      }
      // li on the MFMA pipe: every output row of ones-A mfma = sum_k p[k][q]
      liacc[0] = MFMA16(ones4, pb[0], liacc[0]);
      liacc[1] = MFMA16(ones4, pb[1], liacc[1]);
    }
    __syncthreads();
  }

#pragma unroll
  for (int j = 0; j < 2; ++j) {
    const float rl = 1.0f / liacc[j][0];  // all rows/quads hold the full sum
    const int qj = qb + j * 16 + l15;
    u16* mp = mix + ((size_t)b * NS + qj) * ND + h * DHD + quad * 4;
#pragma unroll
    for (int g = 0; g < 4; ++g) {
      ushort4v o;
#pragma unroll
      for (int r = 0; r < 4; ++r) o[r] = f2bf(O[j][g][r] * rl);
      *(ushort4v*)(mp + g * 16) = o;
    }
  }
}

// ---------------------------------------------------------------------------
// Kernel 3: out projection, fp32 output to (S,B,D). 2-phase + XCD swizzle.
// ---------------------------------------------------------------------------
__global__ __launch_bounds__(256) void out_gemm(
    const u16* __restrict__ A, const u16* __restrict__ Wb,
    const float* __restrict__ bias, float* __restrict__ out) {
  __shared__ __align__(16) u16 p0A[128][32];
  __shared__ __align__(16) u16 p0B[128][32];
  __shared__ __align__(16) u16 p1A[128][32];
  __shared__ __align__(16) u16 p1B[128][32];
  const int tid = threadIdx.x;
  const int lane = tid & 63, wave = tid >> 6;
  const int l15 = lane & 15, quad = lane >> 4;
  const int wm = wave & 1, wn = wave >> 1;
  // XCD swizzle: L in [0,384). xcd=L&7, i=L>>3 in [0,48):
  // m = xcd+8*(i&7), n = i>>3 in [0,6). Bijective.
  const int L = (int)blockIdx.x + 64 * (int)blockIdx.y;
  const int xcd = L & 7, i = L >> 3;
  const int mblk = (xcd + 8 * (i & 7)) * 128;
  const int nblk = (i >> 3) * 128;

  floatx4 acc[4][4];
#pragma unroll
  for (int i2 = 0; i2 < 4; ++i2)
#pragma unroll
    for (int j = 0; j < 4; ++j) acc[i2][j] = (floatx4)0.f;

  const int lr = lane >> 2;
  const int lc = (lane & 3) * 8;
  const int c0 = wave * 2;
  const int r0 = c0 * 16 + lr, r1 = r0 + 16;
  const u16* ga0 = A + (mblk + r0) * ND + lc;
  const u16* ga1 = A + (mblk + r1) * ND + lc;
  const u16* gb0 = Wb + (nblk + r0) * ND + lc;
  const u16* gb1 = Wb + (nblk + r1) * ND + lc;

  GEMM_STAGE(p0, 0);
  __syncthreads();
  for (int kt = 0; kt < 24; kt += 2) {
    GEMM_STAGE(p1, (kt + 1) * 32);
    GEMM_COMPUTE(p0);
    __syncthreads();
    if (kt + 2 < 24) GEMM_STAGE(p0, (kt + 2) * 32);
    GEMM_COMPUTE(p1);
    __syncthreads();
  }

#pragma unroll
  for (int mt = 0; mt < 4; ++mt) {
#pragma unroll
    for (int r = 0; r < 4; ++r) {
      const int gm = mblk + wm * 64 + mt * 16 + quad * 4 + r;
      const int b = gm >> 10, s = gm & 1023;
#pragma unroll
      for (int nt = 0; nt < 4; ++nt) {
        const int gn = nblk + wn * 64 + nt * 16 + l15;
        out[(s * NB + b) * ND + gn] = acc[mt][nt][r] + bias[gn];
      }
    }
  }
}

extern "C" void kernel_launch(void* const* d_in, const int* in_sizes, int n_in,
                              void* d_out, int out_size, void* d_ws, size_t ws_size,
                              hipStream_t stream) {
  const float* X  = (const float*)d_in[0];
  const float* W  = (const float*)d_in[1];
  const float* Bi = (const float*)d_in[2];
  const float* Ow = (const float*)d_in[3];
  const float* Ob = (const float*)d_in[4];
  float* out = (float*)d_out;   // [q | k | v | out], each S*B*D fp32

  u16* Xb  = (u16*)d_ws;            // 6291456  (m-major dense, m=b*1024+s)
  u16* Wb  = Xb  + 6291456;         // 1769472
  u16* Owb = Wb  + 1769472;         // 589824
  u16* Vt  = Owb + 589824;          // 6291456  (b,h,c,s)
  u16* Kb  = Vt  + 6291456;         // 6291456  (b,h,s,c)
  u16* mix = Kb  + 6291456;         // 6291456  (b,s,d)

  cvt3<<<CVT_B0 + CVT_B1 + CVT_B2, 256, 0, stream>>>(X, Xb, W, Wb, Ow, Owb);
  qkv_gemm<<<dim3(64, 18), 256, 0, stream>>>(Xb, Wb, Bi, out);
  prep<<<dim3(32, 96, 2), 256, 0, stream>>>(out + QKV_OUT_STRIDE,
                                            out + 2 * QKV_OUT_STRIDE, Kb, Vt);
  attn<<<dim3(8, 96), 256, 0, stream>>>(out, Kb, Vt, mix);
  out_gemm<<<dim3(64, 6), 256, 0, stream>>>(mix, Owb, Ob, out + 3 * QKV_OUT_STRIDE);
}

// Round 10
// 230.435 us; speedup vs baseline: 1.0733x; 1.0226x over previous
//
#include <hip/hip_runtime.h>
#include <hip/hip_bf16.h>

// S=1024, B=8, D=768, H=12, DH=64, PROMPT_NUM=8 (tokens=1016). I/O fp32.
// bf16 MFMA compute, fp32 accum. Attention: S^T = K*Q^T so the QK accumulator
// (row=key, col=q) IS the B-fragment of the 16x16x16 PV MFMA (P stays in
// registers). K/V tiles staged cooperatively in LDS, reg-buffered prefetch.
// R6: GEMM staging = m97 recipe (global_load_lds width=16, linear LDS).
// R7: attn P-pack via v_cvt_pk_bf16_f32; attn grid XCD-swizzle.
// R8: GEMM 2-phase LDS double-buffer. R9: GEMM XCD swizzle.
// R12: attn softmax exp2-domain Q prescale + ones-MFMA li.
// R13: Xb m-major dense (CONFIRMED WIN: 244.9 -> 235.6 us; layout, not
//     schedule, was qkv's 2.7x gap vs out_gemm).
// R15: (a) attn KVBLK 64->128: one barrier pair per 128 keys (32->16
//     barriers/WG), 4-reg prefetch per matrix; LDS 35.8 KB (4 WGs/CU).
//     (b) T5 setprio(1) around attn's pure-MFMA PV+li cluster (m191: +4-7%).
//     (c) prep K-pass fused into qkv epilogue (coalesced u16 runs,
//     bit-identical f2bf of the same fp32 value); prep is now V-only
//     (deletes a 25 MB fp32 read + half the prep work).
// NOTE: MFMA16/GLD16/SETPRIO gated on __HIP_DEVICE_COMPILE__ — host pass's
// __has_builtin() returns false for amdgcn builtins.

typedef unsigned short u16;
typedef __attribute__((ext_vector_type(8))) short short8;    // 8 bf16 (K=32 frag)
typedef __attribute__((ext_vector_type(4))) short short4v;   // 4 bf16 (K=16 frag)
typedef __attribute__((ext_vector_type(4))) float floatx4;   // MFMA C/D frag
typedef __attribute__((ext_vector_type(4))) unsigned short ushort4v;
typedef __attribute__((ext_vector_type(2))) unsigned int uint2v;

#define NB 8
#define NS 1024
#define NH 12
#define ND 768
#define DHD 64
#define TOKENS 1016
#define QKV_OUT_STRIDE 6291456  // S*B*D elements per output tensor

#if __has_builtin(__builtin_amdgcn_exp2f)
#define EXP2(x) __builtin_amdgcn_exp2f(x)
#else
#define EXP2(x) exp2f(x)
#endif

#if defined(__HIP_DEVICE_COMPILE__)
  #if __has_builtin(__builtin_amdgcn_mfma_f32_16x16x16bf16_1k)
    #define MFMA16(a, b, c) __builtin_amdgcn_mfma_f32_16x16x16bf16_1k(a, b, c, 0, 0, 0)
  #else
    #define MFMA16(a, b, c) __builtin_amdgcn_mfma_f32_16x16x16_bf16(a, b, c, 0, 0, 0)
  #endif
  #define GLD16(g, l)                                                        \
    __builtin_amdgcn_global_load_lds(                                        \
        (const __attribute__((address_space(1))) void*)(g),                  \
        (__attribute__((address_space(3))) void*)(l), 16, 0, 0)
  #define SETPRIO(n) __builtin_amdgcn_s_setprio(n)
#else
  #define MFMA16(a, b, c) (c)   // host pass: dead code, never executed
  #define GLD16(g, l) ((void)0)
  #define SETPRIO(n) ((void)0)
#endif

__device__ __forceinline__ u16 f2bf(float f) {
  union { float f; unsigned u; } c; c.f = f;
  return (u16)((c.u + 0x7fffu + ((c.u >> 16) & 1u)) >> 16);  // RNE
}

// ---------------------------------------------------------------------------
// Kernel 0: fp32 -> bf16 for X, in_proj_weight, out_w. 4 elems/thread.
// X is additionally permuted to m-major dense rows: m = b*1024 + s.
// ---------------------------------------------------------------------------
#define CVT_B0 6144   // X:  6291456/1024
#define CVT_B1 1728   // W:  1769472/1024
#define CVT_B2 576    // Ow: 589824/1024
__global__ __launch_bounds__(256) void cvt3(
    const float* __restrict__ s0, u16* __restrict__ d0,
    const float* __restrict__ s1, u16* __restrict__ d1,
    const float* __restrict__ s2, u16* __restrict__ d2) {
  int blk = blockIdx.x;
  if (blk < CVT_B0) {
    // X: read (s,b,d) flat, write row m = b*1024+s dense.
    const int i = (blk * 256 + (int)threadIdx.x) * 4;
    const float4 v = *(const float4*)(s0 + i);
    const int sb = i / ND;            // s*8 + b
    const int dd = i - sb * ND;       // 4-aligned, stays in-row (4 | 768)
    const int m = ((sb & 7) << 10) | (sb >> 3);
    ushort4v o;
    o.x = f2bf(v.x); o.y = f2bf(v.y); o.z = f2bf(v.z); o.w = f2bf(v.w);
    *(ushort4v*)(d0 + m * ND + dd) = o;
    return;
  }
  const float* s; u16* d;
  if (blk < CVT_B0 + CVT_B1) { s = s1; d = d1; blk -= CVT_B0; }
  else { s = s2; d = d2; blk -= CVT_B0 + CVT_B1; }
  const int i = (blk * 256 + (int)threadIdx.x) * 4;
  const float4 v = *(const float4*)(s + i);
  ushort4v o;
  o.x = f2bf(v.x); o.y = f2bf(v.y); o.z = f2bf(v.z); o.w = f2bf(v.w);
  *(ushort4v*)(d + i) = o;
}

// ---------------------------------------------------------------------------
// Kernel 1: QKV projection. 128x128 tile/WG, 4 waves, 4x4 of 16x16x32 MFMA.
// 2-phase pipeline + XCD swizzle + dense A. Epilogue also emits bf16 Kb
// (b,h,s,c) for the K segment (R15c) — coalesced 32B u16 runs.
// ---------------------------------------------------------------------------
#define GEMM_STAGE(buf, k0)                                                  \
  do {                                                                       \
    GLD16(ga0 + (k0), &buf##A[c0 * 16][0]);                                  \
    GLD16(ga1 + (k0), &buf##A[c0 * 16 + 16][0]);                             \
    GLD16(gb0 + (k0), &buf##B[c0 * 16][0]);                                  \
    GLD16(gb1 + (k0), &buf##B[c0 * 16 + 16][0]);                             \
  } while (0)

#define GEMM_COMPUTE(buf)                                                    \
  do {                                                                       \
    short8 af[4], bfr[4];                                                    \
    _Pragma("unroll")                                                        \
    for (int mt = 0; mt < 4; ++mt)                                           \
      af[mt] = *(const short8*)&buf##A[wm * 64 + mt * 16 + l15][quad * 8];   \
    _Pragma("unroll")                                                        \
    for (int nt = 0; nt < 4; ++nt)                                           \
      bfr[nt] = *(const short8*)&buf##B[wn * 64 + nt * 16 + l15][quad * 8];  \
    _Pragma("unroll")                                                        \
    for (int mt = 0; mt < 4; ++mt)                                           \
      _Pragma("unroll")                                                      \
      for (int nt = 0; nt < 4; ++nt)                                         \
        acc[mt][nt] = __builtin_amdgcn_mfma_f32_16x16x32_bf16(               \
            af[mt], bfr[nt], acc[mt][nt], 0, 0, 0);                          \
  } while (0)

__global__ __launch_bounds__(256) void qkv_gemm(
    const u16* __restrict__ Xb, const u16* __restrict__ Wb,
    const float* __restrict__ bias, float* __restrict__ out,
    u16* __restrict__ Kb) {
  __shared__ __align__(16) u16 p0A[128][32];
  __shared__ __align__(16) u16 p0B[128][32];
  __shared__ __align__(16) u16 p1A[128][32];
  __shared__ __align__(16) u16 p1B[128][32];
  const int tid = threadIdx.x;
  const int lane = tid & 63, wave = tid >> 6;
  const int l15 = lane & 15, quad = lane >> 4;
  const int wm = wave & 1, wn = wave >> 1;
  // XCD swizzle: L in [0,1152). xcd=L&7 -> m-set {xcd,xcd+8,..,xcd+56};
  // n advances every 8 WGs.
  const int L = (int)blockIdx.x + 64 * (int)blockIdx.y;
  const int xcd = L & 7, i = L >> 3;
  const int mblk = (xcd + 8 * (i & 7)) * 128;
  const int nblk = (i >> 3) * 128;

  floatx4 acc[4][4];
#pragma unroll
  for (int i2 = 0; i2 < 4; ++i2)
#pragma unroll
    for (int j = 0; j < 4; ++j) acc[i2][j] = (floatx4)0.f;

  const int lr = lane >> 2;
  const int lc = (lane & 3) * 8;
  const int c0 = wave * 2;
  const int r0 = c0 * 16 + lr, r1 = r0 + 16;
  // Xb is m-major dense: row gm at Xb + gm*ND (R13)
  const u16* ga0 = Xb + (mblk + r0) * ND + lc;
  const u16* ga1 = Xb + (mblk + r1) * ND + lc;
  const u16* gb0 = Wb + (nblk + r0) * ND + lc;
  const u16* gb1 = Wb + (nblk + r1) * ND + lc;

  GEMM_STAGE(p0, 0);
  __syncthreads();
  for (int kt = 0; kt < 24; kt += 2) {
    GEMM_STAGE(p1, (kt + 1) * 32);
    GEMM_COMPUTE(p0);
    __syncthreads();
    if (kt + 2 < 24) GEMM_STAGE(p0, (kt + 2) * 32);
    GEMM_COMPUTE(p1);
    __syncthreads();
  }

  // epilogue: seg is block-uniform (128 | 768 -> n-block within one segment)
  const int seg = nblk / ND;
  const int nbase = nblk - seg * ND;
  float* outp = out + seg * QKV_OUT_STRIDE;
#pragma unroll
  for (int mt = 0; mt < 4; ++mt) {
#pragma unroll
    for (int r = 0; r < 4; ++r) {
      const int gm = mblk + wm * 64 + mt * 16 + quad * 4 + r;
      const int b = gm >> 10, s = gm & 1023;
#pragma unroll
      for (int nt = 0; nt < 4; ++nt) {
        const int gn = nblk + wn * 64 + nt * 16 + l15;
        const int nn = nbase + wn * 64 + nt * 16 + l15;
        const float val = acc[mt][nt][r] + bias[gn];
        outp[(s * NB + b) * ND + nn] = val;
        if (seg == 1) {
          // fused prep-K: Kb[b, h=nn>>6, s, c=nn&63] (bit-identical to prep)
          Kb[(((size_t)b * NH + (nn >> 6)) * NS + s) * DHD + (nn & 63)] =
              f2bf(val);
        }
      }
    }
  }
}

// ---------------------------------------------------------------------------
// Kernel 1b: prep (V only): V fp32 (s,b,h,c) -> Vt[b,h,c,s] bf16 via LDS
// transpose. (K-pass fused into qkv epilogue, R15c.)
// ---------------------------------------------------------------------------
__global__ __launch_bounds__(256) void prep(
    const float* __restrict__ V, u16* __restrict__ Vt) {
  __shared__ u16 tile[DHD][40];
  const int t = threadIdx.x;
  const int bh = blockIdx.y;
  const int b = bh / NH, h = bh % NH;
  const int s0 = blockIdx.x * 32;
  const int sl = t >> 3;
  const int c0 = (t & 7) * 8;
  const int s = s0 + sl;
  const float* src = V + ((s * NB + b) * NH + h) * DHD + c0;
  const float4 v0 = *(const float4*)src;
  const float4 v1 = *(const float4*)(src + 4);
  tile[c0 + 0][sl] = f2bf(v0.x); tile[c0 + 1][sl] = f2bf(v0.y);
  tile[c0 + 2][sl] = f2bf(v0.z); tile[c0 + 3][sl] = f2bf(v0.w);
  tile[c0 + 4][sl] = f2bf(v1.x); tile[c0 + 5][sl] = f2bf(v1.y);
  tile[c0 + 6][sl] = f2bf(v1.z); tile[c0 + 7][sl] = f2bf(v1.w);
  __syncthreads();
  const int c = t >> 2;
  const int so = (t & 3) * 8;
  *(short8*)(Vt + ((size_t)bh * DHD + c) * NS + s0 + so) =
      *(const short8*)&tile[c][so];
}

// ---------------------------------------------------------------------------
// Kernel 2: flash attention. WG = 128 q of one (b,h); wave = 32 q.
// R15a: KVBLK=128 — 8 outer iters, one barrier pair per 128 keys; K/V
// reg-prefetch 4x short8 each. Inner: 2 halves x 4 subs of 16 keys.
// P path (Q pre-scaled by log2e/8; shift-invariance cancels the exp bias):
//   S'^T = mfma32(K, Qs); p = exp2(s'); pack (cvt_pk)
//   O^T[g] = mfma16(V, p, O^T[g]); li = mfma16(ones, p, li)   [setprio 1]
// Grid XCD-swizzled: all 8 q-blocks of one (b,h) on one XCD.
// ---------------------------------------------------------------------------
__global__ __launch_bounds__(256) void attn(
    const float* __restrict__ Q, const u16* __restrict__ Kb,
    const u16* __restrict__ Vt, u16* __restrict__ mix) {
  __shared__ __align__(16) u16 Kt[128][72];   // [key_local][c]
  __shared__ __align__(16) u16 Vs[64][136];   // [c][key_local]
  const int tid = threadIdx.x;
  const int lane = tid & 63, wave = tid >> 6;
  const int l15 = lane & 15, quad = lane >> 4;
  // XCD swizzle: L in [0,768). xcd=L&7, bh=xcd+8*(t>>3), qx=t&7. Bijective.
  const int L = (int)blockIdx.x + 8 * (int)blockIdx.y;
  const int xcd = L & 7, tt = L >> 3;
  const int bh = xcd + 8 * (tt >> 3);
  const int qx = tt & 7;
  const int b = bh / NH, h = bh % NH;
  const int qb = qx * 128 + wave * 32;

  const float SC = 0.125f * 1.44269504089f;    // 1/sqrt(64) * log2(e)

  short8 qf[2][2];
  bool qmask[2];
#pragma unroll
  for (int j = 0; j < 2; ++j) {
    const int qj = qb + j * 16 + l15;
    qmask[j] = (qj == 0 || qj >= TOKENS);
    const float* qp = Q + ((qj * NB + b) * NH + h) * DHD + quad * 8;
#pragma unroll
    for (int e = 0; e < 8; ++e) {
      qf[j][0][e] = (short)f2bf(qp[e] * SC);
      qf[j][1][e] = (short)f2bf(qp[32 + e] * SC);
    }
  }

  floatx4 O[2][4];
#pragma unroll
  for (int j = 0; j < 2; ++j)
#pragma unroll
    for (int g = 0; g < 4; ++g) O[j][g] = (floatx4)0.f;
  floatx4 liacc[2];
  liacc[0] = (floatx4)0.f;
  liacc[1] = (floatx4)0.f;
  short4v ones4;
#pragma unroll
  for (int e = 0; e < 4; ++e) ones4[e] = (short)0x3F80;  // bf16 1.0

  const u16* kg = Kb + (size_t)bh * NS * DHD;  // rows of 64 shorts (s,c)
  const u16* vg = Vt + (size_t)bh * DHD * NS;  // rows of 1024 shorts (c,s)

  // staging (128-key tile): K: thread t -> row t>>1 (0..127), 32-short chunk
  // (t&1)*32. V: thread t -> c-row t>>2 (0..63), 32-short key-chunk (t&3)*32.
  const int krow = tid >> 1;
  const int kcol = (tid & 1) * 32;
  const int vrow = tid >> 2;
  const int vcol = (tid & 3) * 32;

  short8 pk[4], pv[4];
#pragma unroll
  for (int u = 0; u < 4; ++u) {
    pk[u] = *(const short8*)(kg + krow * DHD + kcol + u * 8);
    pv[u] = *(const short8*)(vg + vrow * NS + vcol + u * 8);
  }

  for (int it = 0; it < 8; ++it) {
#pragma unroll
    for (int u = 0; u < 4; ++u) {
      *(short8*)&Kt[krow][kcol + u * 8] = pk[u];
      *(short8*)&Vs[vrow][vcol + u * 8] = pv[u];
    }
    __syncthreads();
    if (it < 7) {
      const int k0 = (it + 1) * 128;
#pragma unroll
      for (int u = 0; u < 4; ++u) {
        pk[u] = *(const short8*)(kg + (k0 + krow) * DHD + kcol + u * 8);
        pv[u] = *(const short8*)(vg + vrow * NS + k0 + vcol + u * 8);
      }
    }
#pragma unroll
    for (int half = 0; half < 2; ++half) {
      // keys >= 1016: it==7, half==1, sub==3, quad>=2
      const bool mrow = (it == 7) && (half == 1) && (quad >= 2);
#pragma unroll
      for (int sub = 0; sub < 4; ++sub) {
        const int kr = half * 64 + sub * 16 + l15;
        const short8 kf0 = *(const short8*)&Kt[kr][quad * 8];
        const short8 kf1 = *(const short8*)&Kt[kr][32 + quad * 8];
        short4v pb[2];
#pragma unroll
        for (int j = 0; j < 2; ++j) {
          floatx4 a = (floatx4)0.f;
          a = __builtin_amdgcn_mfma_f32_16x16x32_bf16(kf0, qf[j][0], a, 0, 0, 0);
          a = __builtin_amdgcn_mfma_f32_16x16x32_bf16(kf1, qf[j][1], a, 0, 0, 0);
          float p[4];
#pragma unroll
          for (int r = 0; r < 4; ++r) p[r] = EXP2(a[r]);
          if (sub == 3 && mrow && qmask[j]) {
#pragma unroll
            for (int r = 0; r < 4; ++r) p[r] = 0.f;
          }
          __hip_bfloat162 w0 = __float22bfloat162_rn(make_float2(p[0], p[1]));
          __hip_bfloat162 w1 = __float22bfloat162_rn(make_float2(p[2], p[3]));
          uint2v pw;
          pw.x = *(const unsigned*)&w0;
          pw.y = *(const unsigned*)&w1;
          pb[j] = __builtin_bit_cast(short4v, pw);
        }
        SETPRIO(1);
#pragma unroll
        for (int g = 0; g < 4; ++g) {
          const short4v vf =
              *(const short4v*)&Vs[g * 16 + l15][half * 64 + sub * 16 + quad * 4];
          O[0][g] = MFMA16(vf, pb[0], O[0][g]);
          O[1][g] = MFMA16(vf, pb[1], O[1][g]);
        }
        liacc[0] = MFMA16(ones4, pb[0], liacc[0]);
        liacc[1] = MFMA16(ones4, pb[1], liacc[1]);
        SETPRIO(0);
      }
    }
    __syncthreads();
  }

#pragma unroll
  for (int j = 0; j < 2; ++j) {
    const float rl = 1.0f / liacc[j][0];  // all rows/quads hold the full sum
    const int qj = qb + j * 16 + l15;
    u16* mp = mix + ((size_t)b * NS + qj) * ND + h * DHD + quad * 4;
#pragma unroll
    for (int g = 0; g < 4; ++g) {
      ushort4v o;
#pragma unroll
      for (int r = 0; r < 4; ++r) o[r] = f2bf(O[j][g][r] * rl);
      *(ushort4v*)(mp + g * 16) = o;
    }
  }
}

// ---------------------------------------------------------------------------
// Kernel 3: out projection, fp32 output to (S,B,D). 2-phase + XCD swizzle.
// ---------------------------------------------------------------------------
__global__ __launch_bounds__(256) void out_gemm(
    const u16* __restrict__ A, const u16* __restrict__ Wb,
    const float* __restrict__ bias, float* __restrict__ out) {
  __shared__ __align__(16) u16 p0A[128][32];
  __shared__ __align__(16) u16 p0B[128][32];
  __shared__ __align__(16) u16 p1A[128][32];
  __shared__ __align__(16) u16 p1B[128][32];
  const int tid = threadIdx.x;
  const int lane = tid & 63, wave = tid >> 6;
  const int l15 = lane & 15, quad = lane >> 4;
  const int wm = wave & 1, wn = wave >> 1;
  const int L = (int)blockIdx.x + 64 * (int)blockIdx.y;
  const int xcd = L & 7, i = L >> 3;
  const int mblk = (xcd + 8 * (i & 7)) * 128;
  const int nblk = (i >> 3) * 128;

  floatx4 acc[4][4];
#pragma unroll
  for (int i2 = 0; i2 < 4; ++i2)
#pragma unroll
    for (int j = 0; j < 4; ++j) acc[i2][j] = (floatx4)0.f;

  const int lr = lane >> 2;
  const int lc = (lane & 3) * 8;
  const int c0 = wave * 2;
  const int r0 = c0 * 16 + lr, r1 = r0 + 16;
  const u16* ga0 = A + (mblk + r0) * ND + lc;
  const u16* ga1 = A + (mblk + r1) * ND + lc;
  const u16* gb0 = Wb + (nblk + r0) * ND + lc;
  const u16* gb1 = Wb + (nblk + r1) * ND + lc;

  GEMM_STAGE(p0, 0);
  __syncthreads();
  for (int kt = 0; kt < 24; kt += 2) {
    GEMM_STAGE(p1, (kt + 1) * 32);
    GEMM_COMPUTE(p0);
    __syncthreads();
    if (kt + 2 < 24) GEMM_STAGE(p0, (kt + 2) * 32);
    GEMM_COMPUTE(p1);
    __syncthreads();
  }

#pragma unroll
  for (int mt = 0; mt < 4; ++mt) {
#pragma unroll
    for (int r = 0; r < 4; ++r) {
      const int gm = mblk + wm * 64 + mt * 16 + quad * 4 + r;
      const int b = gm >> 10, s = gm & 1023;
#pragma unroll
      for (int nt = 0; nt < 4; ++nt) {
        const int gn = nblk + wn * 64 + nt * 16 + l15;
        out[(s * NB + b) * ND + gn] = acc[mt][nt][r] + bias[gn];
      }
    }
  }
}

extern "C" void kernel_launch(void* const* d_in, const int* in_sizes, int n_in,
                              void* d_out, int out_size, void* d_ws, size_t ws_size,
                              hipStream_t stream) {
  const float* X  = (const float*)d_in[0];
  const float* W  = (const float*)d_in[1];
  const float* Bi = (const float*)d_in[2];
  const float* Ow = (const float*)d_in[3];
  const float* Ob = (const float*)d_in[4];
  float* out = (float*)d_out;   // [q | k | v | out], each S*B*D fp32

  u16* Xb  = (u16*)d_ws;            // 6291456  (m-major dense, m=b*1024+s)
  u16* Wb  = Xb  + 6291456;         // 1769472
  u16* Owb = Wb  + 1769472;         // 589824
  u16* Vt  = Owb + 589824;          // 6291456  (b,h,c,s)
  u16* Kb  = Vt  + 6291456;         // 6291456  (b,h,s,c)
  u16* mix = Kb  + 6291456;         // 6291456  (b,s,d)

  cvt3<<<CVT_B0 + CVT_B1 + CVT_B2, 256, 0, stream>>>(X, Xb, W, Wb, Ow, Owb);
  qkv_gemm<<<dim3(64, 18), 256, 0, stream>>>(Xb, Wb, Bi, out, Kb);
  prep<<<dim3(32, 96), 256, 0, stream>>>(out + 2 * QKV_OUT_STRIDE, Vt);
  attn<<<dim3(8, 96), 256, 0, stream>>>(out, Kb, Vt, mix);
  out_gemm<<<dim3(64, 6), 256, 0, stream>>>(mix, Owb, Ob, out + 3 * QKV_OUT_STRIDE);
}